// Round 1
// baseline (520.959 us; speedup 1.0000x reference)
//
#include <hip/hip_runtime.h>
#include <hip/hip_bf16.h>
#include <stdint.h>

#define EPS_BN 1e-5f

// Problem sizes (fixed by setup_inputs)
constexpr int Fn = 32;    // frames
constexpr int Pn = 64;    // peds per frame
constexpr int Bn = 2048;  // batch = Fn*Pn
constexpr int Hn = 128;   // h_dim
constexpr int En = 64;    // embed dim
constexpr int Mn = 512;   // layer1 out (GEMM K)
constexpr int Dn = 1024;  // layer2 out

using bf16x8 = __attribute__((ext_vector_type(8))) short;
using f32x4  = __attribute__((ext_vector_type(4))) float;

// ---------------------------------------------------------------------------
// prep0: Wr = We @ W1[:E]  (2 x 512), cb = be @ W1[:E] + b1  (512)
// ---------------------------------------------------------------------------
__global__ void prep0(const float* __restrict__ We, const float* __restrict__ be,
                      const float* __restrict__ W1, const float* __restrict__ b1,
                      float* __restrict__ Wr, float* __restrict__ cb) {
  int m = threadIdx.x;  // 512 threads
  float w0 = 0.f, w1 = 0.f, c = 0.f;
  for (int e = 0; e < En; ++e) {
    float w = W1[e * Mn + m];
    w0 += We[e] * w;
    w1 += We[En + e] * w;
    c  += be[e] * w;
  }
  Wr[m]      = w0;
  Wr[Mn + m] = w1;
  cb[m]      = c + b1[m];
}

// ---------------------------------------------------------------------------
// prep1: per batch-row r (serves as both j and i):
//   A[r][m]  = pos_r @ Wr + h_r @ W1[E:] + cb        (fp32)
//   Ag[r][m] = A*s1 + t1 ;  Qg[r][m] = (pos_r@Wr)*s1 (both fp32 in ws)
// Block handles 8 rows so W1[E:] is read 256x total instead of 2048x.
// ---------------------------------------------------------------------------
__global__ void prep1(const float* __restrict__ hs, const float* __restrict__ pos,
                      const float* __restrict__ W1,
                      const float* __restrict__ g1, const float* __restrict__ beta1,
                      const float* __restrict__ rm1, const float* __restrict__ rv1,
                      const float* __restrict__ Wr, const float* __restrict__ cb,
                      float* __restrict__ Agf, float* __restrict__ Qgf) {
  int rb = blockIdx.x * 8;  // 256 blocks
  int m  = threadIdx.x;     // 512 threads
  __shared__ float hsh[8 * Hn];
  __shared__ float psh[16];
  for (int idx = m; idx < 8 * Hn; idx += Mn) hsh[idx] = hs[rb * Hn + idx];
  if (m < 16) psh[m] = pos[rb * 2 + m];
  __syncthreads();

  float s  = g1[m] * rsqrtf(rv1[m] + EPS_BN);
  float tt = beta1[m] - rm1[m] * s;
  float wr0 = Wr[m], wr1 = Wr[Mn + m], c = cb[m];

  float acc[8];
#pragma unroll
  for (int ri = 0; ri < 8; ++ri) acc[ri] = c;
  for (int e = 0; e < Hn; ++e) {
    float w = W1[(En + e) * Mn + m];
#pragma unroll
    for (int ri = 0; ri < 8; ++ri) acc[ri] += hsh[ri * Hn + e] * w;
  }
#pragma unroll
  for (int ri = 0; ri < 8; ++ri) {
    float q = psh[ri * 2] * wr0 + psh[ri * 2 + 1] * wr1;
    Agf[(rb + ri) * Mn + m] = (acc[ri] + q) * s + tt;
    Qgf[(rb + ri) * Mn + m] = q * s;
  }
}

// ---------------------------------------------------------------------------
// prep2: W2t[d][k] = bf16(W2[k][d] * s2[d])  (transposed, BN2-scale folded)
//        c2[d] = b2[d]*s2[d] + beta2[d] - rm2[d]*s2[d]
// 64x64 LDS tile transpose.
// ---------------------------------------------------------------------------
__global__ void prep2(const float* __restrict__ W2, const float* __restrict__ g2,
                      const float* __restrict__ beta2, const float* __restrict__ rm2,
                      const float* __restrict__ rv2, const float* __restrict__ b2,
                      __hip_bfloat16* __restrict__ W2t, float* __restrict__ c2) {
  __shared__ float tile[64][65];
  int d0 = blockIdx.x * 64;  // 16 blocks in x
  int k0 = blockIdx.y * 64;  // 8 blocks in y
  int t  = threadIdx.x;      // 256
  int col  = t & 63;
  int row4 = t >> 6;
#pragma unroll
  for (int rr = 0; rr < 16; ++rr) {
    int row = rr * 4 + row4;
    tile[row][col] = W2[(k0 + row) * Dn + d0 + col];
  }
  __syncthreads();
#pragma unroll
  for (int rr = 0; rr < 16; ++rr) {
    int dd = rr * 4 + row4;
    int d  = d0 + dd;
    float s = g2[d] * rsqrtf(rv2[d] + EPS_BN);
    W2t[(size_t)d * Mn + k0 + col] = __float2bfloat16(tile[col][dd] * s);
  }
  if (blockIdx.y == 0 && t < 64) {
    int d = d0 + t;
    float s = g2[d] * rsqrtf(rv2[d] + EPS_BN);
    c2[d] = b2[d] * s + beta2[d] - rm2[d] * s;
  }
}

// ---------------------------------------------------------------------------
// Main fused GEMM + max-pool.
// Block = (row-tile rt: 128 rows = 2 i's x 64 j's of one frame) x (col-tile ct: 128 d).
// A = relu(Ag[f,j,:] - Qg[f,i,:]) constructed on the fly into LDS (bf16, pitch 40).
// B = W2t streamed per 32-k chunk. 16x16x32 bf16 MFMA, 4 waves 2x2, 4x4 tiles each.
// Epilogue: +c2, relu, max over the 64 j rows, one exclusive write per (i,d).
// ---------------------------------------------------------------------------
__launch_bounds__(256, 3)
__global__ void gemm_pool(const float* __restrict__ Agf, const float* __restrict__ Qgf,
                          const unsigned short* __restrict__ W2t,
                          const float* __restrict__ c2, float* __restrict__ out) {
  constexpr int LDA = 40;  // bf16 elems per LDS row (32 data + 8 pad -> 80B pitch)
  __shared__ unsigned short As[128 * LDA];
  __shared__ unsigned short Bs[128 * LDA];

  int ct = blockIdx.x;  // 0..7
  int rt = blockIdx.y;  // 0..1023
  int f  = rt >> 5;
  int i0 = (rt & 31) * 2;
  int d0 = ct * 128;

  int t    = threadIdx.x;
  int lane = t & 63;
  int wave = t >> 6;
  int wm   = wave & 1;   // row half (which i)
  int wn   = wave >> 1;  // col half

  // staging assignment: tile row r = t&127, k-half kh = t>>7 (16 elems each)
  int r  = t & 127;
  int kh = t >> 7;
  int j  = r & 63;
  int il = r >> 6;
  const float* Arow = Agf + (f * Pn + j) * Mn;
  const float* Qrow = Qgf + (f * Pn + i0 + il) * Mn;
  const unsigned short* Brow = W2t + (size_t)(d0 + r) * Mn;

  f32x4 acc[4][4];
#pragma unroll
  for (int mt = 0; mt < 4; ++mt)
#pragma unroll
    for (int nt = 0; nt < 4; ++nt) acc[mt][nt] = (f32x4){0.f, 0.f, 0.f, 0.f};

  int mrow = lane & 15;
  int koff = (lane >> 4) * 8;

  for (int kc = 0; kc < Mn / 32; ++kc) {
    int k0 = kc * 32;
    // ---- stage A: x2 = relu(Ag - Qg), 16 fp32 -> 16 bf16 (truncation) ----
    const float4* ap = (const float4*)(Arow + k0 + kh * 16);
    const float4* qp = (const float4*)(Qrow + k0 + kh * 16);
    uint32_t pk[8];
#pragma unroll
    for (int v = 0; v < 4; ++v) {
      float4 a = ap[v];
      float4 q = qp[v];
      float x0 = fmaxf(a.x - q.x, 0.f);
      float x1 = fmaxf(a.y - q.y, 0.f);
      float x2 = fmaxf(a.z - q.z, 0.f);
      float x3 = fmaxf(a.w - q.w, 0.f);
      uint32_t u0 = __builtin_bit_cast(uint32_t, x0);
      uint32_t u1 = __builtin_bit_cast(uint32_t, x1);
      uint32_t u2 = __builtin_bit_cast(uint32_t, x2);
      uint32_t u3 = __builtin_bit_cast(uint32_t, x3);
      pk[v * 2 + 0] = (u0 >> 16) | (u1 & 0xFFFF0000u);
      pk[v * 2 + 1] = (u2 >> 16) | (u3 & 0xFFFF0000u);
    }
    uint4 w0 = {pk[0], pk[1], pk[2], pk[3]};
    uint4 w1 = {pk[4], pk[5], pk[6], pk[7]};
    *(uint4*)&As[r * LDA + kh * 16]     = w0;
    *(uint4*)&As[r * LDA + kh * 16 + 8] = w1;
    // ---- stage B: copy 16 bf16 from W2t ----
    const uint4* bp = (const uint4*)(Brow + k0 + kh * 16);
    uint4 b0 = bp[0];
    uint4 b1 = bp[1];
    *(uint4*)&Bs[r * LDA + kh * 16]     = b0;
    *(uint4*)&Bs[r * LDA + kh * 16 + 8] = b1;

    __syncthreads();

    bf16x8 af[4], bg[4];
#pragma unroll
    for (int mt = 0; mt < 4; ++mt)
      af[mt] = *(const bf16x8*)&As[(wm * 64 + mt * 16 + mrow) * LDA + koff];
#pragma unroll
    for (int nt = 0; nt < 4; ++nt)
      bg[nt] = *(const bf16x8*)&Bs[(wn * 64 + nt * 16 + mrow) * LDA + koff];
#pragma unroll
    for (int mt = 0; mt < 4; ++mt)
#pragma unroll
      for (int nt = 0; nt < 4; ++nt)
        acc[mt][nt] = __builtin_amdgcn_mfma_f32_16x16x32_bf16(af[mt], bg[nt],
                                                              acc[mt][nt], 0, 0, 0);
    __syncthreads();
  }

  // ---- epilogue: +c2, relu, max over 64 j rows, write out[f*P + i][d] ----
  // C layout: col = lane&15, row = (lane>>4)*4 + reg. All 4 m-tiles of this wave
  // belong to i = i0 + wm; rows cover all 64 j.
  float red[4];
#pragma unroll
  for (int nt = 0; nt < 4; ++nt) {
    int d = d0 + wn * 64 + nt * 16 + (lane & 15);
    float c2v = c2[d];
    float mx = 0.f;  // = max(0, max_j y2) = max_j relu(y2)
#pragma unroll
    for (int mt = 0; mt < 4; ++mt)
#pragma unroll
      for (int rg = 0; rg < 4; ++rg)
        mx = fmaxf(mx, acc[mt][nt][rg] + c2v);
    mx = fmaxf(mx, __shfl_xor(mx, 16));
    mx = fmaxf(mx, __shfl_xor(mx, 32));
    red[nt] = mx;
  }
  int nts = lane >> 4;
  float val = (nts == 0) ? red[0] : (nts == 1) ? red[1] : (nts == 2) ? red[2] : red[3];
  int row_out = f * Pn + i0 + wm;
  out[row_out * Dn + d0 + wn * 64 + nts * 16 + (lane & 15)] = val;
}

// ---------------------------------------------------------------------------
extern "C" void kernel_launch(void* const* d_in, const int* in_sizes, int n_in,
                              void* d_out, int out_size, void* d_ws, size_t ws_size,
                              hipStream_t stream) {
  const float* hs    = (const float*)d_in[0];   // (1,B,H)
  const float* pos   = (const float*)d_in[1];   // (B,2)
  // d_in[2] seq_start_end: unused (equal-size frames, P=64)
  const float* We    = (const float*)d_in[3];
  const float* be    = (const float*)d_in[4];
  const float* W1    = (const float*)d_in[5];
  const float* b1    = (const float*)d_in[6];
  const float* g1    = (const float*)d_in[7];
  const float* beta1 = (const float*)d_in[8];
  const float* W2    = (const float*)d_in[9];
  const float* b2    = (const float*)d_in[10];
  const float* g2    = (const float*)d_in[11];
  const float* beta2 = (const float*)d_in[12];
  const float* rm1   = (const float*)d_in[13];
  const float* rv1   = (const float*)d_in[14];
  const float* rm2   = (const float*)d_in[15];
  const float* rv2   = (const float*)d_in[16];

  char* ws = (char*)d_ws;
  // layout (bytes): Wr 4096 | cb 2048 | c2 4096 | Agf 4MB | Qgf 4MB | W2t 1MB
  float* Wr  = (float*)(ws + 0);
  float* cb  = (float*)(ws + 4096);
  float* c2  = (float*)(ws + 6144);
  float* Agf = (float*)(ws + 10240);
  float* Qgf = (float*)(ws + 10240 + 4194304);
  __hip_bfloat16* W2t = (__hip_bfloat16*)(ws + 10240 + 2 * 4194304);
  float* out = (float*)d_out;

  prep0<<<1, Mn, 0, stream>>>(We, be, W1, b1, Wr, cb);
  prep2<<<dim3(Dn / 64, Mn / 64), 256, 0, stream>>>(W2, g2, beta2, rm2, rv2, b2, W2t, c2);
  prep1<<<Bn / 8, Mn, 0, stream>>>(hs, pos, W1, g1, beta1, rm1, rv1, Wr, cb, Agf, Qgf);
  gemm_pool<<<dim3(Dn / 128, (Bn * Pn) / 128), 256, 0, stream>>>(
      Agf, Qgf, (const unsigned short*)W2t, c2, out);
}

// Round 2
// 277.430 us; speedup vs baseline: 1.8778x; 1.8778x over previous
//
#include <hip/hip_runtime.h>
#include <hip/hip_bf16.h>
#include <stdint.h>

#define EPS_BN 1e-5f

// Problem sizes (fixed by setup_inputs)
constexpr int Fn = 32;    // frames
constexpr int Pn = 64;    // peds per frame
constexpr int Bn = 2048;  // batch = Fn*Pn
constexpr int Hn = 128;   // h_dim
constexpr int En = 64;    // embed dim
constexpr int Mn = 512;   // layer1 out (GEMM K)
constexpr int Dn = 1024;  // layer2 out

using bf16x8 = __attribute__((ext_vector_type(8))) short;
using f32x4  = __attribute__((ext_vector_type(4))) float;

static __device__ __forceinline__ float    bcf(uint32_t u) { return __builtin_bit_cast(float, u); }
static __device__ __forceinline__ uint32_t bcu(float f)    { return __builtin_bit_cast(uint32_t, f); }
static __device__ __forceinline__ unsigned short bfbits(float f) {
  return __builtin_bit_cast(unsigned short, __float2bfloat16(f));
}

// ---------------------------------------------------------------------------
// prep0: Wr = We @ W1[:E]  (2 x 512), cb = be @ W1[:E] + b1  (512)
// ---------------------------------------------------------------------------
__global__ void prep0(const float* __restrict__ We, const float* __restrict__ be,
                      const float* __restrict__ W1, const float* __restrict__ b1,
                      float* __restrict__ Wr, float* __restrict__ cb) {
  int m = threadIdx.x;  // 512 threads
  float w0 = 0.f, w1 = 0.f, c = 0.f;
  for (int e = 0; e < En; ++e) {
    float w = W1[e * Mn + m];
    w0 += We[e] * w;
    w1 += We[En + e] * w;
    c  += be[e] * w;
  }
  Wr[m]      = w0;
  Wr[Mn + m] = w1;
  cb[m]      = c + b1[m];
}

// ---------------------------------------------------------------------------
// prep1: per batch-row r: Ag/Qg with BN1 folded, emitted in bf16 (RNE).
//   Ag[r][m] = ((h_r@W1h + pos_r@Wr + cb))*s1 + t1 ; Qg[r][m] = (pos_r@Wr)*s1
// ---------------------------------------------------------------------------
__global__ void prep1(const float* __restrict__ hs, const float* __restrict__ pos,
                      const float* __restrict__ W1,
                      const float* __restrict__ g1, const float* __restrict__ beta1,
                      const float* __restrict__ rm1, const float* __restrict__ rv1,
                      const float* __restrict__ Wr, const float* __restrict__ cb,
                      __hip_bfloat16* __restrict__ Agb, __hip_bfloat16* __restrict__ Qgb) {
  int rb = blockIdx.x * 8;  // 256 blocks
  int m  = threadIdx.x;     // 512 threads
  __shared__ float hsh[8 * Hn];
  __shared__ float psh[16];
  for (int idx = m; idx < 8 * Hn; idx += Mn) hsh[idx] = hs[rb * Hn + idx];
  if (m < 16) psh[m] = pos[rb * 2 + m];
  __syncthreads();

  float s  = g1[m] * rsqrtf(rv1[m] + EPS_BN);
  float tt = beta1[m] - rm1[m] * s;
  float wr0 = Wr[m], wr1 = Wr[Mn + m], c = cb[m];

  float acc[8];
#pragma unroll
  for (int ri = 0; ri < 8; ++ri) acc[ri] = c;
  for (int e = 0; e < Hn; ++e) {
    float w = W1[(En + e) * Mn + m];
#pragma unroll
    for (int ri = 0; ri < 8; ++ri) acc[ri] += hsh[ri * Hn + e] * w;
  }
#pragma unroll
  for (int ri = 0; ri < 8; ++ri) {
    float q = psh[ri * 2] * wr0 + psh[ri * 2 + 1] * wr1;
    Agb[(rb + ri) * Mn + m] = __float2bfloat16((acc[ri] + q) * s + tt);
    Qgb[(rb + ri) * Mn + m] = __float2bfloat16(q * s);
  }
}

// ---------------------------------------------------------------------------
// prep2: W2f in MFMA B-fragment granule order, BN2 scale folded, bf16.
// Granule (ntile, kc): lane L holds 8 bf16 = W2[k][d]*s2[d] for
//   d = ntile*16 + (L&15), k = kc*32 + (L>>4)*8 + j (j=0..7).
// c2[d] = b2*s2 + beta2 - rm2*s2.
// ---------------------------------------------------------------------------
__global__ void prep2(const float* __restrict__ W2, const float* __restrict__ g2,
                      const float* __restrict__ beta2, const float* __restrict__ rm2,
                      const float* __restrict__ rv2, const float* __restrict__ b2,
                      uint4* __restrict__ W2f, float* __restrict__ c2) {
  __shared__ float tile[64][65];
  int d0 = blockIdx.x * 64;  // 16 blocks in x
  int k0 = blockIdx.y * 64;  // 8 blocks in y
  int t  = threadIdx.x;      // 256
  int col  = t & 63;
  int row4 = t >> 6;
#pragma unroll
  for (int rr = 0; rr < 16; ++rr) {
    int row = rr * 4 + row4;
    tile[row][col] = W2[(k0 + row) * Dn + d0 + col];  // tile[k_local][d_local]
  }
  __syncthreads();

  int lane = t & 63, sel = t >> 6;
  int dl = sel * 16 + (lane & 15);
  int d  = d0 + dl;
  float s = g2[d] * rsqrtf(rv2[d] + EPS_BN);
#pragma unroll
  for (int kcl = 0; kcl < 2; ++kcl) {
    int kb = kcl * 32 + (lane >> 4) * 8;
    uint32_t w[4];
#pragma unroll
    for (int h = 0; h < 4; ++h) {
      unsigned short u0 = bfbits(tile[kb + 2 * h][dl] * s);
      unsigned short u1 = bfbits(tile[kb + 2 * h + 1][dl] * s);
      w[h] = (uint32_t)u0 | ((uint32_t)u1 << 16);
    }
    int ntile = (d0 >> 4) + sel;
    int kc    = (k0 >> 5) + kcl;
    W2f[(ntile * 16 + kc) * 64 + lane] = (uint4){w[0], w[1], w[2], w[3]};
  }
  if (blockIdx.y == 0 && t < 64) {
    int dd = d0 + t;
    float ss = g2[dd] * rsqrtf(rv2[dd] + EPS_BN);
    c2[dd] = b2[dd] * ss + beta2[dd] - rm2[dd] * ss;
  }
}

// ---------------------------------------------------------------------------
// Main fused GEMM + max-pool, restructured K-loop:
//  - A constructed in registers (bf16 Ag/Qg loads, one Ag row shared by both i's)
//    directly in MFMA A-fragment granule order -> conflict-free b128 LDS traffic.
//  - Double-buffered LDS, ONE raw barrier per kc (lgkmcnt(0) only, NO vmcnt
//    drain) so next-kc global loads stay in flight across the barrier.
//  - Safety: each wave's own lgkmcnt(0) before its barrier arrival drains its
//    ds_reads of buffer p, so rewriting buffer p two iterations later is safe.
// ---------------------------------------------------------------------------
__launch_bounds__(256, 3)
__global__ void gemm_pool(const __hip_bfloat16* __restrict__ Agb,
                          const __hip_bfloat16* __restrict__ Qgb,
                          const uint4* __restrict__ W2f,
                          const float* __restrict__ c2, float* __restrict__ out) {
  __shared__ unsigned short As[2][4096];  // 8 granules x 64 lanes x 8 bf16 = 8KB each
  __shared__ unsigned short Bs[2][4096];

  int ct = blockIdx.x;  // 0..7  (d-tile)
  int rt = blockIdx.y;  // 0..1023 (row-tile: frame f, i-pair)
  int f  = rt >> 5;
  int i0 = (rt & 31) * 2;

  int t    = threadIdx.x;
  int lane = t & 63;
  int g    = t >> 6;     // wave index = A-granule (0..3); also stages granule g+4
  int wm   = g & 1;      // which i of the pair
  int wn   = g >> 1;     // which d-half

  int jA    = g * 16 + (lane & 15);   // Ag row (same for both staged slices)
  int koct8 = (lane >> 4) * 8;        // k-octet within the 32-k chunk

  const uint4* aP  = (const uint4*)(Agb + (f * Pn + jA) * Mn + koct8);        // +4/kc
  const uint4* q0P = (const uint4*)(Qgb + (f * Pn + i0) * Mn + koct8);
  const uint4* q1P = (const uint4*)(Qgb + (f * Pn + i0 + 1) * Mn + koct8);
  const uint4* b0P = W2f + ((ct * 8 + g) * 16) * 64 + lane;                   // +64/kc
  const uint4* b1P = W2f + ((ct * 8 + g + 4) * 16) * 64 + lane;

  // prologue: kc=0 loads
  uint4 rA  = aP[0];
  uint4 rQ0 = q0P[0];
  uint4 rQ1 = q1P[0];
  uint4 rB0 = b0P[0];
  uint4 rB1 = b1P[0];

  f32x4 acc[4][4];
#pragma unroll
  for (int mt = 0; mt < 4; ++mt)
#pragma unroll
    for (int nt = 0; nt < 4; ++nt) acc[mt][nt] = (f32x4){0.f, 0.f, 0.f, 0.f};

  int slot0 = (g * 64 + lane) * 8;        // ushort index of slice g
  int slot1 = ((g + 4) * 64 + lane) * 8;  // slice g+4

#pragma unroll 2
  for (int kc = 0; kc < 16; ++kc) {
    int p = kc & 1;
    // ---- construct x2 = relu(Ag - Qg) for both i's, pack to bf16 ----
    uint4 x0, x1;
#pragma unroll
    for (int w = 0; w < 4; ++w) {
      uint32_t aw  = ((const uint32_t*)&rA)[w];
      float alo = bcf(aw << 16), ahi = bcf(aw & 0xFFFF0000u);
      uint32_t q0w = ((const uint32_t*)&rQ0)[w];
      uint32_t q1w = ((const uint32_t*)&rQ1)[w];
      float x0lo = fmaxf(alo - bcf(q0w << 16), 0.f);
      float x0hi = fmaxf(ahi - bcf(q0w & 0xFFFF0000u), 0.f);
      float x1lo = fmaxf(alo - bcf(q1w << 16), 0.f);
      float x1hi = fmaxf(ahi - bcf(q1w & 0xFFFF0000u), 0.f);
      ((uint32_t*)&x0)[w] = (bcu(x0lo) >> 16) | (bcu(x0hi) & 0xFFFF0000u);
      ((uint32_t*)&x1)[w] = (bcu(x1lo) >> 16) | (bcu(x1hi) & 0xFFFF0000u);
    }
    *(uint4*)&As[p][slot0] = x0;   // granule g    (rows g*16.., i = i0)
    *(uint4*)&As[p][slot1] = x1;   // granule g+4  (same j rows, i = i0+1)
    *(uint4*)&Bs[p][slot0] = rB0;
    *(uint4*)&Bs[p][slot1] = rB1;

    // barrier WITHOUT vmcnt drain: LDS writes visible, global loads in flight
    asm volatile("s_waitcnt lgkmcnt(0)\n\ts_barrier" ::: "memory");

    // ---- prefetch kc+1 (issued before MFMA phase; latency hidden) ----
    int kn = (kc < 15) ? kc + 1 : 15;
    rA  = aP[kn * 4];
    rQ0 = q0P[kn * 4];
    rQ1 = q1P[kn * 4];
    rB0 = b0P[kn * 64];
    rB1 = b1P[kn * 64];

    // ---- LDS -> frags -> MFMA (lane-contiguous b128, conflict-free) ----
    bf16x8 af[4], bg[4];
#pragma unroll
    for (int mt = 0; mt < 4; ++mt)
      af[mt] = *(const bf16x8*)&As[p][((wm * 4 + mt) * 64 + lane) * 8];
#pragma unroll
    for (int nt = 0; nt < 4; ++nt)
      bg[nt] = *(const bf16x8*)&Bs[p][((wn * 4 + nt) * 64 + lane) * 8];
#pragma unroll
    for (int mt = 0; mt < 4; ++mt)
#pragma unroll
      for (int nt = 0; nt < 4; ++nt)
        acc[mt][nt] = __builtin_amdgcn_mfma_f32_16x16x32_bf16(af[mt], bg[nt],
                                                              acc[mt][nt], 0, 0, 0);
  }

  // ---- epilogue: +c2, relu, max over 64 j rows, write out[f*P + i][d] ----
  int d0 = ct * 128;
  float red[4];
#pragma unroll
  for (int nt = 0; nt < 4; ++nt) {
    int d = d0 + wn * 64 + nt * 16 + (lane & 15);
    float c2v = c2[d];
    float mx = 0.f;  // = max(0, max_j y2) = max_j relu(y2)
#pragma unroll
    for (int mt = 0; mt < 4; ++mt)
#pragma unroll
      for (int rg = 0; rg < 4; ++rg)
        mx = fmaxf(mx, acc[mt][nt][rg] + c2v);
    mx = fmaxf(mx, __shfl_xor(mx, 16));
    mx = fmaxf(mx, __shfl_xor(mx, 32));
    red[nt] = mx;
  }
  int nts = lane >> 4;
  float val = (nts == 0) ? red[0] : (nts == 1) ? red[1] : (nts == 2) ? red[2] : red[3];
  int row_out = f * Pn + i0 + wm;
  out[row_out * Dn + d0 + wn * 64 + nts * 16 + (lane & 15)] = val;
}

// ---------------------------------------------------------------------------
extern "C" void kernel_launch(void* const* d_in, const int* in_sizes, int n_in,
                              void* d_out, int out_size, void* d_ws, size_t ws_size,
                              hipStream_t stream) {
  const float* hs    = (const float*)d_in[0];   // (1,B,H)
  const float* pos   = (const float*)d_in[1];   // (B,2)
  // d_in[2] seq_start_end: unused (equal-size frames, P=64)
  const float* We    = (const float*)d_in[3];
  const float* be    = (const float*)d_in[4];
  const float* W1    = (const float*)d_in[5];
  const float* b1    = (const float*)d_in[6];
  const float* g1    = (const float*)d_in[7];
  const float* beta1 = (const float*)d_in[8];
  const float* W2    = (const float*)d_in[9];
  const float* b2    = (const float*)d_in[10];
  const float* g2    = (const float*)d_in[11];
  const float* beta2 = (const float*)d_in[12];
  const float* rm1   = (const float*)d_in[13];
  const float* rv1   = (const float*)d_in[14];
  const float* rm2   = (const float*)d_in[15];
  const float* rv2   = (const float*)d_in[16];

  char* ws = (char*)d_ws;
  // layout (bytes): Wr 4K | cb 2K | c2 4K | Agb 2M | Qgb 2M | W2f 1M   (~5.3 MB)
  float* Wr  = (float*)(ws + 0);
  float* cb  = (float*)(ws + 4096);
  float* c2  = (float*)(ws + 6144);
  __hip_bfloat16* Agb = (__hip_bfloat16*)(ws + 10240);
  __hip_bfloat16* Qgb = (__hip_bfloat16*)(ws + 10240 + 2097152);
  uint4* W2f = (uint4*)(ws + 10240 + 2 * 2097152);
  float* out = (float*)d_out;

  prep0<<<1, Mn, 0, stream>>>(We, be, W1, b1, Wr, cb);
  prep2<<<dim3(Dn / 64, Mn / 64), 256, 0, stream>>>(W2, g2, beta2, rm2, rv2, b2, W2f, c2);
  prep1<<<Bn / 8, Mn, 0, stream>>>(hs, pos, W1, g1, beta1, rm1, rv1, Wr, cb, Agb, Qgb);
  gemm_pool<<<dim3(Dn / 128, (Bn * Pn) / 128), 256, 0, stream>>>(Agb, Qgb, W2f, c2, out);
}